// Round 1
// baseline (52.595 us; speedup 1.0000x reference)
//
#include <hip/hip_runtime.h>
#include <math.h>

#define N_SRC 12000
#define N_TAR 12000
#define NT_CHUNKS 32
#define CHUNK 375            // N_TAR / NT_CHUNKS (exact)
#define SRC_PER_BLOCK 1024   // 256 threads * 4 src each
#define SRC_BLOCKS 12        // ceil(N_SRC / SRC_PER_BLOCK)

// ---------------------------------------------------------------------------
// Kernel 1: brute-force NN partial argmin.
// score(i,j) = |tar_j(3d)|^2 - 2 * dot3(tsrc_i, tar_j)   (row-constant terms
// dropped; equivalent argmin to reference's expression since tar.w == 1).
// Each thread owns 4 source points; each block scans one chunk of 375 targets
// staged in LDS as [tx,ty,tz, tx^2+ty^2+tz^2].
// ---------------------------------------------------------------------------
__global__ __launch_bounds__(256) void nn_partial_kernel(
    const float* __restrict__ T,
    const float* __restrict__ src,
    const float* __restrict__ tar,
    float* __restrict__ pval,
    int*   __restrict__ pidx)
{
    __shared__ float4 lds[CHUNK];
    const int tid   = threadIdx.x;
    const int sblk  = blockIdx.x;
    const int chunk = blockIdx.y;
    const int jbase = chunk * CHUNK;

    // rows of T (tsrc = T @ p)
    const float T00=T[0],  T01=T[1],  T02=T[2],  T03=T[3];
    const float T10=T[4],  T11=T[5],  T12=T[6],  T13=T[7];
    const float T20=T[8],  T21=T[9],  T22=T[10], T23=T[11];

    const float4* tar4 = (const float4*)tar;
    for (int j = tid; j < CHUNK; j += 256) {
        float4 t = tar4[jbase + j];
        float n3 = t.x*t.x + t.y*t.y + t.z*t.z;
        lds[j] = make_float4(t.x, t.y, t.z, n3);
    }
    __syncthreads();

    float sx[4], sy[4], sz[4], mval[4];
    int   mi[4], si[4];
    #pragma unroll
    for (int k = 0; k < 4; ++k) {
        int i = sblk * SRC_PER_BLOCK + k * 256 + tid;
        si[k] = i;
        float px = 0.f, py = 0.f, pz = 0.f, pw = 1.f;
        if (i < N_SRC) {
            float4 p = ((const float4*)src)[i];
            px = p.x; py = p.y; pz = p.z; pw = p.w;
        }
        float tx = T00*px + T01*py + T02*pz + T03*pw;
        float ty = T10*px + T11*py + T12*pz + T13*pw;
        float tz = T20*px + T21*py + T22*pz + T23*pw;
        sx[k] = -2.0f * tx;
        sy[k] = -2.0f * ty;
        sz[k] = -2.0f * tz;
        mval[k] = INFINITY;
        mi[k]   = 0;
    }

    #pragma unroll 5
    for (int j = 0; j < CHUNK; ++j) {
        float4 t = lds[j];
        #pragma unroll
        for (int k = 0; k < 4; ++k) {
            float s = fmaf(sx[k], t.x, fmaf(sy[k], t.y, fmaf(sz[k], t.z, t.w)));
            if (s < mval[k]) { mval[k] = s; mi[k] = jbase + j; }
        }
    }

    #pragma unroll
    for (int k = 0; k < 4; ++k) {
        if (si[k] < N_SRC) {
            pval[chunk * N_SRC + si[k]] = mval[k];
            pidx[chunk * N_SRC + si[k]] = mi[k];
        }
    }
}

// ---------------------------------------------------------------------------
// Kernel 2: combine chunk partials (first-min tie-break), then per-point
// covariance congruence, 3x3 adjugate inverse, Mahalanobis form; block
// reduction -> one double atomicAdd per block.
// ---------------------------------------------------------------------------
__global__ __launch_bounds__(256) void mah_kernel(
    const float* __restrict__ T,
    const float* __restrict__ src,
    const float* __restrict__ tar,
    const float* __restrict__ cs,   // covs_src  [N][16]
    const float* __restrict__ ct,   // covs_tar  [N][16]
    const float* __restrict__ pval,
    const int*   __restrict__ pidx,
    double* __restrict__ accum)
{
    const int i = blockIdx.x * 256 + threadIdx.x;
    float mah = 0.0f;

    if (i < N_SRC) {
        // combine partial argmins (ascending chunk, strict < => first min)
        float best = INFINITY; int bidx = 0;
        #pragma unroll
        for (int c = 0; c < NT_CHUNKS; ++c) {
            float v  = pval[c * N_SRC + i];
            int   ix = pidx[c * N_SRC + i];
            if (v < best) { best = v; bidx = ix; }
        }

        float Tm[4][4];
        #pragma unroll
        for (int a = 0; a < 16; ++a) ((float*)Tm)[a] = T[a];

        float C[4][4];
        #pragma unroll
        for (int a = 0; a < 16; ++a) ((float*)C)[a] = cs[i * 16 + a];

        // B[j][c] = sum_k C[j][k] * T[c][k]   (c = 0..2)
        float B[4][3];
        #pragma unroll
        for (int j = 0; j < 4; ++j)
            #pragma unroll
            for (int c = 0; c < 3; ++c)
                B[j][c] = C[j][0]*Tm[c][0] + C[j][1]*Tm[c][1]
                        + C[j][2]*Tm[c][2] + C[j][3]*Tm[c][3];

        // M[r][c] = sum_j T[r][j] * B[j][c]  + covs_tar[bidx][r][c]
        const float* ctb = ct + (size_t)bidx * 16;
        float M[3][3];
        #pragma unroll
        for (int r = 0; r < 3; ++r)
            #pragma unroll
            for (int c = 0; c < 3; ++c)
                M[r][c] = Tm[r][0]*B[0][c] + Tm[r][1]*B[1][c]
                        + Tm[r][2]*B[2][c] + Tm[r][3]*B[3][c]
                        + ctb[r * 4 + c];

        const float a_ = M[0][0], b_ = M[0][1], c_ = M[0][2];
        const float d_ = M[1][0], e_ = M[1][1], f_ = M[1][2];
        const float g_ = M[2][0], h_ = M[2][1], i_ = M[2][2];

        const float A0 = e_*i_ - f_*h_;
        const float A1 = f_*g_ - d_*i_;
        const float A2 = d_*h_ - e_*g_;
        const float det = a_*A0 + b_*A1 + c_*A2;
        const float rdet = 1.0f / det;

        float inv[3][3];
        inv[0][0] = A0 * rdet;
        inv[0][1] = (c_*h_ - b_*i_) * rdet;
        inv[0][2] = (b_*f_ - c_*e_) * rdet;
        inv[1][0] = A1 * rdet;
        inv[1][1] = (a_*i_ - c_*g_) * rdet;
        inv[1][2] = (c_*d_ - a_*f_) * rdet;
        inv[2][0] = A2 * rdet;
        inv[2][1] = (b_*g_ - a_*h_) * rdet;
        inv[2][2] = (a_*e_ - b_*d_) * rdet;

        // loss branch: pT = src @ T  (columns of T)
        float4 p = ((const float4*)src)[i];
        float p0 = p.x*Tm[0][0] + p.y*Tm[1][0] + p.z*Tm[2][0] + p.w*Tm[3][0];
        float p1 = p.x*Tm[0][1] + p.y*Tm[1][1] + p.z*Tm[2][1] + p.w*Tm[3][1];
        float p2 = p.x*Tm[0][2] + p.y*Tm[1][2] + p.z*Tm[2][2] + p.w*Tm[3][2];

        const float4 tp = ((const float4*)tar)[bidx];
        const float r0 = tp.x - p0;
        const float r1 = tp.y - p1;
        const float r2 = tp.z - p2;

        mah = r0*(inv[0][0]*r0 + inv[0][1]*r1 + inv[0][2]*r2)
            + r1*(inv[1][0]*r0 + inv[1][1]*r1 + inv[1][2]*r2)
            + r2*(inv[2][0]*r0 + inv[2][1]*r1 + inv[2][2]*r2);
    }

    // block reduction: wave shuffle + LDS across 4 waves
    float v = mah;
    #pragma unroll
    for (int off = 32; off > 0; off >>= 1)
        v += __shfl_down(v, off, 64);

    __shared__ float wsum[4];
    if ((threadIdx.x & 63) == 0) wsum[threadIdx.x >> 6] = v;
    __syncthreads();
    if (threadIdx.x == 0) {
        float s = wsum[0] + wsum[1] + wsum[2] + wsum[3];
        atomicAdd(accum, (double)s);
    }
}

__global__ void finalize_kernel(const double* __restrict__ accum,
                                float* __restrict__ out)
{
    out[0] = (float)(accum[0] / (double)N_SRC);
}

extern "C" void kernel_launch(void* const* d_in, const int* in_sizes, int n_in,
                              void* d_out, int out_size, void* d_ws, size_t ws_size,
                              hipStream_t stream) {
    const float* T   = (const float*)d_in[0];
    const float* src = (const float*)d_in[1];
    const float* tar = (const float*)d_in[2];
    const float* cs  = (const float*)d_in[3];
    const float* ct  = (const float*)d_in[4];
    float* out = (float*)d_out;

    char* ws = (char*)d_ws;
    double* accum = (double*)ws;                                   // 8 B
    float*  pval  = (float*)(ws + 16);                             // 32*12000*4
    int*    pidx  = (int*)(ws + 16 + NT_CHUNKS * N_SRC * sizeof(float));

    hipMemsetAsync(accum, 0, sizeof(double), stream);

    dim3 g1(SRC_BLOCKS, NT_CHUNKS);
    nn_partial_kernel<<<g1, 256, 0, stream>>>(T, src, tar, pval, pidx);

    mah_kernel<<<(N_SRC + 255) / 256, 256, 0, stream>>>(
        T, src, tar, cs, ct, pval, pidx, accum);

    finalize_kernel<<<1, 1, 0, stream>>>(accum, out);
}

// Round 2
// 46.888 us; speedup vs baseline: 1.1217x; 1.1217x over previous
//
#include <hip/hip_runtime.h>
#include <math.h>

#define N_SRC 12000
#define N_TAR 12000
#define NT_CHUNKS 48
#define CHUNK 250            // N_TAR / NT_CHUNKS (exact)
#define SRC_PER_BLOCK 512    // 256 threads * 2 src each
#define SRC_BLOCKS 24        // ceil(N_SRC / SRC_PER_BLOCK)
#define MAH_BLOCKS 47        // ceil(N_SRC / 256)

// ---------------------------------------------------------------------------
// Kernel 1: brute-force NN partial argmin.
// score(i,j) = |tar_j(3d)|^2 - 2 * dot3(tsrc_i, tar_j)   (row-constant terms
// dropped; equivalent argmin to reference's d2 since tar.w == 1 exactly and
// tsrc.w is row-constant).  Each thread owns 2 source points; each block
// scans one chunk of 250 targets staged in LDS as [tx,ty,tz, |t3|^2].
// ---------------------------------------------------------------------------
__global__ __launch_bounds__(256) void nn_partial_kernel(
    const float* __restrict__ T,
    const float* __restrict__ src,
    const float* __restrict__ tar,
    float* __restrict__ pval,
    int*   __restrict__ pidx)
{
    __shared__ float4 lds[CHUNK];
    const int tid   = threadIdx.x;
    const int sblk  = blockIdx.x;
    const int chunk = blockIdx.y;
    const int jbase = chunk * CHUNK;

    // rows of T (tsrc = T @ p)
    const float T00=T[0],  T01=T[1],  T02=T[2],  T03=T[3];
    const float T10=T[4],  T11=T[5],  T12=T[6],  T13=T[7];
    const float T20=T[8],  T21=T[9],  T22=T[10], T23=T[11];

    const float4* tar4 = (const float4*)tar;
    if (tid < CHUNK) {
        float4 t = tar4[jbase + tid];
        float n3 = t.x*t.x + t.y*t.y + t.z*t.z;
        lds[tid] = make_float4(t.x, t.y, t.z, n3);
    }
    __syncthreads();

    float sx[2], sy[2], sz[2], mval[2];
    int   mi[2], si[2];
    #pragma unroll
    for (int k = 0; k < 2; ++k) {
        int i = sblk * SRC_PER_BLOCK + k * 256 + tid;
        si[k] = i;
        float px = 0.f, py = 0.f, pz = 0.f, pw = 1.f;
        if (i < N_SRC) {
            float4 p = ((const float4*)src)[i];
            px = p.x; py = p.y; pz = p.z; pw = p.w;
        }
        float tx = T00*px + T01*py + T02*pz + T03*pw;
        float ty = T10*px + T11*py + T12*pz + T13*pw;
        float tz = T20*px + T21*py + T22*pz + T23*pw;
        sx[k] = -2.0f * tx;
        sy[k] = -2.0f * ty;
        sz[k] = -2.0f * tz;
        mval[k] = INFINITY;
        mi[k]   = 0;
    }

    #pragma unroll 5
    for (int j = 0; j < CHUNK; ++j) {
        float4 t = lds[j];
        #pragma unroll
        for (int k = 0; k < 2; ++k) {
            float s = fmaf(sx[k], t.x, fmaf(sy[k], t.y, fmaf(sz[k], t.z, t.w)));
            if (s < mval[k]) { mval[k] = s; mi[k] = jbase + j; }
        }
    }

    #pragma unroll
    for (int k = 0; k < 2; ++k) {
        if (si[k] < N_SRC) {
            pval[chunk * N_SRC + si[k]] = mval[k];
            pidx[chunk * N_SRC + si[k]] = mi[k];
        }
    }
}

// ---------------------------------------------------------------------------
// Kernel 2: combine chunk partials (ascending chunk order + strict < gives
// the reference's first-min tie-break), then covariance congruence, 3x3
// adjugate inverse, Mahalanobis form; block reduce -> per-block partial sum
// (no atomics, no zero-init needed: every block writes its slot).
// ---------------------------------------------------------------------------
__global__ __launch_bounds__(256) void mah_kernel(
    const float* __restrict__ T,
    const float* __restrict__ src,
    const float* __restrict__ tar,
    const float* __restrict__ cs,   // covs_src  [N][16]
    const float* __restrict__ ct,   // covs_tar  [N][16]
    const float* __restrict__ pval,
    const int*   __restrict__ pidx,
    float* __restrict__ bsum)
{
    const int i = blockIdx.x * 256 + threadIdx.x;
    float mah = 0.0f;

    if (i < N_SRC) {
        float best = INFINITY; int bidx = 0;
        #pragma unroll
        for (int c = 0; c < NT_CHUNKS; ++c) {
            float v  = pval[c * N_SRC + i];
            int   ix = pidx[c * N_SRC + i];
            if (v < best) { best = v; bidx = ix; }
        }

        float Tm[4][4];
        #pragma unroll
        for (int a = 0; a < 16; ++a) ((float*)Tm)[a] = T[a];

        float C[4][4];
        #pragma unroll
        for (int a = 0; a < 16; ++a) ((float*)C)[a] = cs[i * 16 + a];

        // B[j][c] = sum_k C[j][k] * T[c][k]   (c = 0..2)
        float B[4][3];
        #pragma unroll
        for (int j = 0; j < 4; ++j)
            #pragma unroll
            for (int c = 0; c < 3; ++c)
                B[j][c] = C[j][0]*Tm[c][0] + C[j][1]*Tm[c][1]
                        + C[j][2]*Tm[c][2] + C[j][3]*Tm[c][3];

        // M[r][c] = sum_j T[r][j] * B[j][c] + covs_tar[bidx][r][c]
        const float* ctb = ct + (size_t)bidx * 16;
        float M[3][3];
        #pragma unroll
        for (int r = 0; r < 3; ++r)
            #pragma unroll
            for (int c = 0; c < 3; ++c)
                M[r][c] = Tm[r][0]*B[0][c] + Tm[r][1]*B[1][c]
                        + Tm[r][2]*B[2][c] + Tm[r][3]*B[3][c]
                        + ctb[r * 4 + c];

        const float a_ = M[0][0], b_ = M[0][1], c_ = M[0][2];
        const float d_ = M[1][0], e_ = M[1][1], f_ = M[1][2];
        const float g_ = M[2][0], h_ = M[2][1], i_ = M[2][2];

        const float A0 = e_*i_ - f_*h_;
        const float A1 = f_*g_ - d_*i_;
        const float A2 = d_*h_ - e_*g_;
        const float det = a_*A0 + b_*A1 + c_*A2;
        const float rdet = 1.0f / det;

        float inv[3][3];
        inv[0][0] = A0 * rdet;
        inv[0][1] = (c_*h_ - b_*i_) * rdet;
        inv[0][2] = (b_*f_ - c_*e_) * rdet;
        inv[1][0] = A1 * rdet;
        inv[1][1] = (a_*i_ - c_*g_) * rdet;
        inv[1][2] = (c_*d_ - a_*f_) * rdet;
        inv[2][0] = A2 * rdet;
        inv[2][1] = (b_*g_ - a_*h_) * rdet;
        inv[2][2] = (a_*e_ - b_*d_) * rdet;

        // loss branch: pT = src @ T  (columns of T)
        float4 p = ((const float4*)src)[i];
        float p0 = p.x*Tm[0][0] + p.y*Tm[1][0] + p.z*Tm[2][0] + p.w*Tm[3][0];
        float p1 = p.x*Tm[0][1] + p.y*Tm[1][1] + p.z*Tm[2][1] + p.w*Tm[3][1];
        float p2 = p.x*Tm[0][2] + p.y*Tm[1][2] + p.z*Tm[2][2] + p.w*Tm[3][2];

        const float4 tp = ((const float4*)tar)[bidx];
        const float r0 = tp.x - p0;
        const float r1 = tp.y - p1;
        const float r2 = tp.z - p2;

        mah = r0*(inv[0][0]*r0 + inv[0][1]*r1 + inv[0][2]*r2)
            + r1*(inv[1][0]*r0 + inv[1][1]*r1 + inv[1][2]*r2)
            + r2*(inv[2][0]*r0 + inv[2][1]*r1 + inv[2][2]*r2);
    }

    // block reduction: wave shuffle + LDS across 4 waves (deterministic)
    float v = mah;
    #pragma unroll
    for (int off = 32; off > 0; off >>= 1)
        v += __shfl_down(v, off, 64);

    __shared__ float wsum[4];
    if ((threadIdx.x & 63) == 0) wsum[threadIdx.x >> 6] = v;
    __syncthreads();
    if (threadIdx.x == 0)
        bsum[blockIdx.x] = wsum[0] + wsum[1] + wsum[2] + wsum[3];
}

// ---------------------------------------------------------------------------
// Kernel 3: reduce the 47 block partials in double, write the mean.
// ---------------------------------------------------------------------------
__global__ __launch_bounds__(64) void finalize_kernel(
    const float* __restrict__ bsum,
    float* __restrict__ out)
{
    const int tid = threadIdx.x;
    double v = (tid < MAH_BLOCKS) ? (double)bsum[tid] : 0.0;
    #pragma unroll
    for (int off = 32; off > 0; off >>= 1)
        v += __shfl_down(v, off, 64);
    if (tid == 0)
        out[0] = (float)(v / (double)N_SRC);
}

extern "C" void kernel_launch(void* const* d_in, const int* in_sizes, int n_in,
                              void* d_out, int out_size, void* d_ws, size_t ws_size,
                              hipStream_t stream) {
    const float* T   = (const float*)d_in[0];
    const float* src = (const float*)d_in[1];
    const float* tar = (const float*)d_in[2];
    const float* cs  = (const float*)d_in[3];
    const float* ct  = (const float*)d_in[4];
    float* out = (float*)d_out;

    char* ws = (char*)d_ws;
    float* pval = (float*)ws;                                      // 48*12000*4
    int*   pidx = (int*)(ws + (size_t)NT_CHUNKS * N_SRC * 4);      // 48*12000*4
    float* bsum = (float*)(ws + (size_t)NT_CHUNKS * N_SRC * 8);    // 47 floats

    dim3 g1(SRC_BLOCKS, NT_CHUNKS);
    nn_partial_kernel<<<g1, 256, 0, stream>>>(T, src, tar, pval, pidx);

    mah_kernel<<<MAH_BLOCKS, 256, 0, stream>>>(
        T, src, tar, cs, ct, pval, pidx, bsum);

    finalize_kernel<<<1, 64, 0, stream>>>(bsum, out);
}